// Round 14
// baseline (747.690 us; speedup 1.0000x reference)
//
#include <hip/hip_runtime.h>
#include <hip/hip_bf16.h>
#include <math.h>

#define INPUT 2048
#define HIDDEN 128
#define BATCH 64
#define TSTEPS 512
#define RB 16
#define KSLICE 4
#define KS (INPUT / KSLICE)  // 512
#define GBK 64
#define SNKT (KS / GBK)      // 8

typedef _Float16 half_t;
typedef __attribute__((ext_vector_type(2))) _Float16 half2_t;
typedef __attribute__((ext_vector_type(8))) _Float16 f16x8;
typedef __attribute__((ext_vector_type(4))) float f32x4;

static __device__ __forceinline__ f16x8 as_f16x8(uint4 v) {
  return __builtin_bit_cast(f16x8, v);
}
static __device__ __forceinline__ unsigned int h2u(half2_t v) {
  return __builtin_bit_cast(unsigned int, v);
}
static __device__ __forceinline__ half2_t pkrtz(float a, float b) {
  return __builtin_bit_cast(half2_t, __builtin_amdgcn_cvt_pkrtz(a, b));
}
static __device__ __forceinline__ float h2f(unsigned short u) {
  return (float)__builtin_bit_cast(half_t, u);
}

static __device__ __forceinline__ float tanh_fast(float x) {
#if __has_builtin(__builtin_amdgcn_exp2f)
  const float e = __builtin_amdgcn_exp2f(x * 2.885390082f);
#else
  const float e = exp2f(x * 2.885390082f);
#endif
  return 1.f - 2.f * __builtin_amdgcn_rcpf(e + 1.f);
}

// ---------------------------------------------------------------------------
// Prep: W_ih f32 -> Wg granule layout; W_hh f32 -> packed half2 (k-major).
// ---------------------------------------------------------------------------
__global__ __launch_bounds__(256) void prep_kernel(
    const float* __restrict__ W_ih, const float* __restrict__ W_hh,
    uint4* __restrict__ Wg, unsigned int* __restrict__ Whh2) {
  const int id = blockIdx.x * 256 + threadIdx.x;  // 32768 threads
  const int col = id & 127;
  const int kc = id >> 7;  // 0..255
  const float4 a = *(const float4*)(W_ih + (size_t)col * INPUT + kc * 8);
  const float4 b = *(const float4*)(W_ih + (size_t)col * INPUT + kc * 8 + 4);
  uint4 q = {h2u(pkrtz(a.x, a.y)), h2u(pkrtz(a.z, a.w)),
             h2u(pkrtz(b.x, b.y)), h2u(pkrtz(b.z, b.w))};
  Wg[(size_t)kc * 128 + col] = q;
  if (id < 8192) {
    float2 p = ((const float2*)W_hh)[id];
    half_t ha = (half_t)p.x, hb = (half_t)p.y;
    Whh2[id] = (unsigned int)__builtin_bit_cast(unsigned short, ha) |
               ((unsigned int)__builtin_bit_cast(unsigned short, hb) << 16);
  }
}

// ---------------------------------------------------------------------------
// Fused producer/consumer.
//   blocks 0..3      : rec, R11-exact STEP (measured 186 us), 16 batch each,
//                      xw layout [t][b][h], flag-gated depth-2 prefetch.
//   blocks 4..2051   : producer (t, slice): t = (bid-4)>>2, s = (bid-4)&3.
//                      R10 GEMM structure over k in [s*512, s*512+512),
//                      all 64 batches of one t. Slice order serialized by
//                      flag[t] acquire/release chain (R9-proven machinery).
// LDS padded to ~64 KB -> 2 blocks/CU: producers run in ~4 dispatch rounds,
// so low-t blocks COMPLETE early (~20 us) and rec overlaps the rest.
// ---------------------------------------------------------------------------
__global__ __launch_bounds__(256) void fused_kernel(
    const float* __restrict__ x, const uint4* __restrict__ Wg,
    const unsigned int* __restrict__ Whh2, const float* __restrict__ b_ih,
    const float* __restrict__ b_hh, const float* __restrict__ W_fc,
    const float* __restrict__ b_fc, half_t* __restrict__ xw,
    int* __restrict__ flags, float* __restrict__ out) {
  __shared__ uint4 sA[2][8][64];         // 16 KB (producer A staging)
  __shared__ half_t st[2][RB][HIDDEN];   // 8 KB (rec state)
  __shared__ float red[256];             // 1 KB
  __shared__ char lds_pad[39 * 1024];    // pad total to ~64 KB -> 2 blocks/CU
  if (flags == nullptr) lds_pad[threadIdx.x] = 1;  // keep pad alive (never true)

  const int tid = threadIdx.x;
  const int lane = tid & 63;
  const int w = tid >> 6;
  const int l15 = lane & 15;

  if (blockIdx.x >= 4) {
    // ========================= producer =========================
    const int p = blockIdx.x - 4;
    const int t = p >> 2;
    const int s = p & 3;

    const int wr = w >> 1, wc = w & 1;
    const int kcl = lane >> 4;
    const int xm = tid & 63, xkq = tid >> 6;
    const float* xsrc =
        x + ((size_t)xm * TSTEPS + t) * INPUT + s * KS + xkq * 16;

    f32x4 acc[2][4];
#pragma unroll
    for (int rt = 0; rt < 2; ++rt)
#pragma unroll
      for (int ct = 0; ct < 4; ++ct) acc[rt][ct] = (f32x4)0.f;

    float bias_c[4];
#pragma unroll
    for (int ct = 0; ct < 4; ++ct) {
      const int col = wc * 64 + ct * 16 + l15;
      bias_c[ct] = b_ih[col] + b_hh[col];
    }

    float4 xva[4], xvb[4];
    uint4 br0[8], br1[8];

    auto XLOAD = [&](int kt, float4* xv) {
      const float4* xs = (const float4*)(xsrc + kt * GBK);
#pragma unroll
      for (int j = 0; j < 4; ++j) xv[j] = xs[j];
    };
    auto XWRITE = [&](int bf, const float4* xv) {
#pragma unroll
      for (int g = 0; g < 2; ++g) {
        uint4 q = {h2u(pkrtz(xv[2 * g].x, xv[2 * g].y)),
                   h2u(pkrtz(xv[2 * g].z, xv[2 * g].w)),
                   h2u(pkrtz(xv[2 * g + 1].x, xv[2 * g + 1].y)),
                   h2u(pkrtz(xv[2 * g + 1].z, xv[2 * g + 1].w))};
        sA[bf][xkq * 2 + g][xm] = q;
      }
    };
    auto BLOAD = [&](int kt, uint4* bb) {
#pragma unroll
      for (int kf = 0; kf < 2; ++kf)
#pragma unroll
        for (int ct = 0; ct < 4; ++ct)
          bb[kf * 4 + ct] = Wg[(size_t)((s * SNKT + kt) * 8 + kf * 4 + kcl) * 128 +
                               wc * 64 + ct * 16 + l15];
    };
    auto COMPUTE = [&](int bf, const uint4* bb) {
      uint4 af[2][2];
#pragma unroll
      for (int kf = 0; kf < 2; ++kf)
#pragma unroll
        for (int rt = 0; rt < 2; ++rt)
          af[kf][rt] = sA[bf][kf * 4 + kcl][wr * 32 + rt * 16 + l15];
#pragma unroll
      for (int kf = 0; kf < 2; ++kf)
#pragma unroll
        for (int rt = 0; rt < 2; ++rt)
#pragma unroll
          for (int ct = 0; ct < 4; ++ct)
            acc[rt][ct] = __builtin_amdgcn_mfma_f32_16x16x32_f16(
                as_f16x8(af[kf][rt]), as_f16x8(bb[kf * 4 + ct]), acc[rt][ct], 0, 0, 0);
    };

    XLOAD(0, xva);
    XLOAD(1, xvb);
    BLOAD(0, br0);
    XWRITE(0, xva);
    __syncthreads();

#pragma unroll 1
    for (int kt = 0; kt < SNKT; kt += 2) {
      BLOAD(kt + 1, br1);
      if (kt + 2 < SNKT) XLOAD(kt + 2, xva);
      COMPUTE(0, br0);
      XWRITE(1, xvb);
      __syncthreads();
      if (kt + 2 < SNKT) BLOAD(kt + 2, br0);
      if (kt + 3 < SNKT) XLOAD(kt + 3, xvb);
      COMPUTE(1, br1);
      if (kt + 2 < SNKT) {
        XWRITE(0, xva);
        __syncthreads();
      }
    }

    // serialized accumulate into xw[t][b][h] (slice order via flag chain)
    if (s != 0) {
      if (tid == 0)
        while (__hip_atomic_load(&flags[t], __ATOMIC_ACQUIRE,
                                 __HIP_MEMORY_SCOPE_AGENT) != s)
          __builtin_amdgcn_s_sleep(1);
      __syncthreads();
    }
    const int rbase = wr * 32 + (lane >> 4) * 4;  // batch row
    half_t* xwt = xw + (size_t)t * (BATCH * HIDDEN);
#pragma unroll
    for (int rt = 0; rt < 2; ++rt)
#pragma unroll
      for (int ct = 0; ct < 4; ++ct) {
        const int col = wc * 64 + ct * 16 + l15;
#pragma unroll
        for (int j = 0; j < 4; ++j) {
          const int row = rbase + rt * 16 + j;
          const size_t idx = (size_t)row * HIDDEN + col;
          if (s == 0) {
            xwt[idx] = (half_t)(acc[rt][ct][j] + bias_c[ct]);
          } else {
            xwt[idx] = (half_t)((float)xwt[idx] + acc[rt][ct][j]);
          }
        }
      }
    __syncthreads();  // drains stores (vmcnt 0) before release
    if (tid == 0)
      __hip_atomic_store(&flags[t], s + 1, __ATOMIC_RELEASE,
                         __HIP_MEMORY_SCOPE_AGENT);
    return;
  }

  // ========================= rec (R11-exact STEP) =========================
  const int blk = blockIdx.x;    // 0..3
  const int bl = lane & 15;      // batch-local
  const int kg = lane >> 4;      // k-group
  const int swz = (bl & 7) << 4; // LDS XOR swizzle

  uint4 afr[2][4];
#pragma unroll
  for (int mi = 0; mi < 2; ++mi)
#pragma unroll
    for (int kt = 0; kt < 4; ++kt)
      afr[mi][kt] = *(const uint4*)(Whh2 + ((size_t)((2 * w + mi) * 16 + bl)) * 64 +
                                    kt * 16 + kg * 4);

#pragma unroll
  for (int i = 0; i < 4; ++i) ((unsigned int*)st)[tid + 256 * i] = 0u;
  __syncthreads();

  // xw layout [t][b][h]: per-t stride = BATCH*HIDDEN = 8192 elements
  const half_t* xb0 = xw + (size_t)(blk * RB + bl) * HIDDEN + w * 32 + kg * 4;
  const half_t* xb1 = xb0 + 16;
#define TSTR ((size_t)(BATCH * HIDDEN))

  float hh[2][4];

  auto aload = [&](int tt) {
    return __hip_atomic_load(&flags[tt], __ATOMIC_ACQUIRE,
                             __HIP_MEMORY_SCOPE_AGENT);
  };
  auto waitf = [&](int tt) {
    while (aload(tt) != KSLICE) __builtin_amdgcn_s_sleep(2);
  };

  auto STEP = [&](const half_t* stR, half_t* stW, ushort4 xc0, ushort4 xc1) {
    uint4 bfr[4];
#pragma unroll
    for (int kt = 0; kt < 4; ++kt) {
      const int off = (bl * 256 + kt * 64 + kg * 16) ^ swz;
      bfr[kt] = *(const uint4*)((const char*)stR + off);
    }
    f32x4 a0, a1;
    a0[0] = h2f(xc0.x); a0[1] = h2f(xc0.y); a0[2] = h2f(xc0.z); a0[3] = h2f(xc0.w);
    a1[0] = h2f(xc1.x); a1[1] = h2f(xc1.y); a1[2] = h2f(xc1.z); a1[3] = h2f(xc1.w);
#pragma unroll
    for (int kt = 0; kt < 4; ++kt) {
      a0 = __builtin_amdgcn_mfma_f32_16x16x32_f16(as_f16x8(afr[0][kt]),
                                                  as_f16x8(bfr[kt]), a0, 0, 0, 0);
      a1 = __builtin_amdgcn_mfma_f32_16x16x32_f16(as_f16x8(afr[1][kt]),
                                                  as_f16x8(bfr[kt]), a1, 0, 0, 0);
    }
#pragma unroll
    for (int j = 0; j < 4; ++j) {
      hh[0][j] = tanh_fast(a0[j]);
      hh[1][j] = tanh_fast(a1[j]);
    }
    uint2 p0 = {h2u(pkrtz(hh[0][0], hh[0][1])), h2u(pkrtz(hh[0][2], hh[0][3]))};
    uint2 p1 = {h2u(pkrtz(hh[1][0], hh[1][1])), h2u(pkrtz(hh[1][2], hh[1][3]))};
    const int w0 = (bl * 256 + (2 * w + 0) * 32 + kg * 8) ^ swz;
    const int w1 = (bl * 256 + (2 * w + 1) * 32 + kg * 8) ^ swz;
    *(uint2*)((char*)stW + w0) = p0;
    *(uint2*)((char*)stW + w1) = p1;
    __syncthreads();
  };

  // prologue: wait for t=0,1
  waitf(0);
  ushort4 xA0 = *(const ushort4*)(xb0);
  ushort4 xA1 = *(const ushort4*)(xb1);
  waitf(1);
  ushort4 xB0 = *(const ushort4*)(xb0 + TSTR);
  ushort4 xB1 = *(const ushort4*)(xb1 + TSTR);

  for (int t2 = 0; t2 < TSTEPS; t2 += 2) {
    const ushort4 c0 = xA0, c1 = xA1;
    int f2 = (t2 + 2 < TSTEPS) ? aload(t2 + 2) : KSLICE;
    STEP(&st[0][0][0], &st[1][0][0], c0, c1);
    if (t2 + 2 < TSTEPS) {
      while (f2 != KSLICE) { __builtin_amdgcn_s_sleep(1); f2 = aload(t2 + 2); }
      xA0 = *(const ushort4*)(xb0 + (size_t)(t2 + 2) * TSTR);
      xA1 = *(const ushort4*)(xb1 + (size_t)(t2 + 2) * TSTR);
    }
    const ushort4 d0 = xB0, d1 = xB1;
    int f3 = (t2 + 3 < TSTEPS) ? aload(t2 + 3) : KSLICE;
    STEP(&st[1][0][0], &st[0][0][0], d0, d1);
    if (t2 + 3 < TSTEPS) {
      while (f3 != KSLICE) { __builtin_amdgcn_s_sleep(1); f3 = aload(t2 + 3); }
      xB0 = *(const ushort4*)(xb0 + (size_t)(t2 + 3) * TSTR);
      xB1 = *(const ushort4*)(xb1 + (size_t)(t2 + 3) * TSTR);
    }
  }

  const float4 wf0 = *(const float4*)&W_fc[(2 * w + 0) * 16 + kg * 4];
  const float4 wf1 = *(const float4*)&W_fc[(2 * w + 1) * 16 + kg * 4];
  float partial = hh[0][0] * wf0.x + hh[0][1] * wf0.y + hh[0][2] * wf0.z +
                  hh[0][3] * wf0.w + hh[1][0] * wf1.x + hh[1][1] * wf1.y +
                  hh[1][2] * wf1.z + hh[1][3] * wf1.w;
  red[tid] = partial;
  __syncthreads();
  if (tid < RB) {
    float ssum = b_fc[0];
#pragma unroll
    for (int q = 0; q < 16; ++q) ssum += red[q * 16 + tid];
    out[blk * RB + tid] = ssum;
  }
}

extern "C" void kernel_launch(void* const* d_in, const int* in_sizes, int n_in,
                              void* d_out, int out_size, void* d_ws, size_t ws_size,
                              hipStream_t stream) {
  const float* x    = (const float*)d_in[0];
  const float* W_ih = (const float*)d_in[1];
  const float* W_hh = (const float*)d_in[2];
  const float* b_ih = (const float*)d_in[3];
  const float* b_hh = (const float*)d_in[4];
  const float* W_fc = (const float*)d_in[5];
  const float* b_fc = (const float*)d_in[6];

  char* ws = (char*)d_ws;
  int*          flags = (int*)ws;                                   // 4 KB
  half_t*       xwf16 = (half_t*)(ws + 4096);                       // 8 MB
  uint4*        Wg    = (uint4*)(ws + 4096 + (8u << 20));           // 512 KB
  unsigned int* Whh2  = (unsigned int*)(ws + 4096 + (8u << 20) + (512u << 10));

  hipMemsetAsync(ws, 0, 4096, stream);  // reset flags each launch
  prep_kernel<<<128, 256, 0, stream>>>(W_ih, W_hh, Wg, Whh2);
  fused_kernel<<<4 + TSTEPS * KSLICE, 256, 0, stream>>>(
      x, Wg, Whh2, b_ih, b_hh, W_fc, b_fc, xwf16, flags, (float*)d_out);
}

// Round 15
// 601.120 us; speedup vs baseline: 1.2438x; 1.2438x over previous
//
#include <hip/hip_runtime.h>
#include <hip/hip_bf16.h>
#include <math.h>

#define INPUT 2048
#define HIDDEN 128
#define BATCH 64
#define TSTEPS 512
#define RB 16
#define GBK 64
#define GNKT (INPUT / GBK)   // 32
#define NPROD 128            // producer blocks; each does TSTEPS/NPROD = 4 t's

typedef _Float16 half_t;
typedef __attribute__((ext_vector_type(2))) _Float16 half2_t;
typedef __attribute__((ext_vector_type(8))) _Float16 f16x8;
typedef __attribute__((ext_vector_type(4))) float f32x4;

static __device__ __forceinline__ f16x8 as_f16x8(uint4 v) {
  return __builtin_bit_cast(f16x8, v);
}
static __device__ __forceinline__ unsigned int h2u(half2_t v) {
  return __builtin_bit_cast(unsigned int, v);
}
static __device__ __forceinline__ half2_t pkrtz(float a, float b) {
  return __builtin_bit_cast(half2_t, __builtin_amdgcn_cvt_pkrtz(a, b));
}
static __device__ __forceinline__ float h2f(unsigned short u) {
  return (float)__builtin_bit_cast(half_t, u);
}

static __device__ __forceinline__ float tanh_fast(float x) {
#if __has_builtin(__builtin_amdgcn_exp2f)
  const float e = __builtin_amdgcn_exp2f(x * 2.885390082f);
#else
  const float e = exp2f(x * 2.885390082f);
#endif
  return 1.f - 2.f * __builtin_amdgcn_rcpf(e + 1.f);
}

// ---------------------------------------------------------------------------
// Prep: W_ih f32 -> Wg granule layout; W_hh f32 -> packed half2 (k-major).
// ---------------------------------------------------------------------------
__global__ __launch_bounds__(256) void prep_kernel(
    const float* __restrict__ W_ih, const float* __restrict__ W_hh,
    uint4* __restrict__ Wg, unsigned int* __restrict__ Whh2) {
  const int id = blockIdx.x * 256 + threadIdx.x;  // 32768 threads
  const int col = id & 127;
  const int kc = id >> 7;  // 0..255
  const float4 a = *(const float4*)(W_ih + (size_t)col * INPUT + kc * 8);
  const float4 b = *(const float4*)(W_ih + (size_t)col * INPUT + kc * 8 + 4);
  uint4 q = {h2u(pkrtz(a.x, a.y)), h2u(pkrtz(a.z, a.w)),
             h2u(pkrtz(b.x, b.y)), h2u(pkrtz(b.z, b.w))};
  Wg[(size_t)kc * 128 + col] = q;
  if (id < 8192) {
    float2 p = ((const float2*)W_hh)[id];
    half_t ha = (half_t)p.x, hb = (half_t)p.y;
    Whh2[id] = (unsigned int)__builtin_bit_cast(unsigned short, ha) |
               ((unsigned int)__builtin_bit_cast(unsigned short, hb) << 16);
  }
}

// ---------------------------------------------------------------------------
// Fused producer/consumer, ZERO producer-producer coupling.
//   blocks 0..3    : rec (R11-exact STEP, 186 us), 16 batch each. Flag-gated
//                    depth-2 prefetch of xw[t][b][h].
//   blocks 4..131  : producers. Block p computes FULL K=2048 for t = p,
//                    p+128, p+256, p+384 (in that order): one 64x128 GEMM
//                    per t, single writer of xw[t], then flag[t]=1 release.
//                    Chunk 1 (t<128) completes ~20 us -> early consumer start;
//                    delivery ~6 t/us >> consumption 2.8 t/us.
// Grid 132 blocks <= 256 CUs: everything resident, no spinning producers.
// ---------------------------------------------------------------------------
__global__ __launch_bounds__(256) void fused_kernel(
    const float* __restrict__ x, const uint4* __restrict__ Wg,
    const unsigned int* __restrict__ Whh2, const float* __restrict__ b_ih,
    const float* __restrict__ b_hh, const float* __restrict__ W_fc,
    const float* __restrict__ b_fc, half_t* __restrict__ xw,
    int* __restrict__ flags, float* __restrict__ out) {
  __shared__ uint4 sA[2][8][64];        // 16 KB (producer A staging)
  __shared__ half_t st[2][RB][HIDDEN];  // 8 KB (rec state)
  __shared__ float red[256];            // 1 KB

  const int tid = threadIdx.x;
  const int lane = tid & 63;
  const int w = tid >> 6;
  const int l15 = lane & 15;

  if (blockIdx.x >= 4) {
    // ========================= producer =========================
    const int pid = blockIdx.x - 4;  // 0..127
    const int wr = w >> 1, wc = w & 1;
    const int kcl = lane >> 4;
    const int xm = tid & 63, xkq = tid >> 6;

    float bias_c[4];
#pragma unroll
    for (int ct = 0; ct < 4; ++ct) {
      const int col = wc * 64 + ct * 16 + l15;
      bias_c[ct] = b_ih[col] + b_hh[col];
    }

#pragma unroll 1
    for (int tc = 0; tc < TSTEPS / NPROD; ++tc) {
      const int t = pid + tc * NPROD;
      const float* xsrc = x + ((size_t)xm * TSTEPS + t) * INPUT + xkq * 16;

      f32x4 acc[2][4];
#pragma unroll
      for (int rt = 0; rt < 2; ++rt)
#pragma unroll
        for (int ct = 0; ct < 4; ++ct) acc[rt][ct] = (f32x4)0.f;

      float4 xva[4], xvb[4];
      uint4 br0[8], br1[8];

      auto XLOAD = [&](int kt, float4* xv) {
        const float4* xs = (const float4*)(xsrc + kt * GBK);
#pragma unroll
        for (int j = 0; j < 4; ++j) xv[j] = xs[j];
      };
      auto XWRITE = [&](int bf, const float4* xv) {
#pragma unroll
        for (int g = 0; g < 2; ++g) {
          uint4 q = {h2u(pkrtz(xv[2 * g].x, xv[2 * g].y)),
                     h2u(pkrtz(xv[2 * g].z, xv[2 * g].w)),
                     h2u(pkrtz(xv[2 * g + 1].x, xv[2 * g + 1].y)),
                     h2u(pkrtz(xv[2 * g + 1].z, xv[2 * g + 1].w))};
          sA[bf][xkq * 2 + g][xm] = q;
        }
      };
      auto BLOAD = [&](int kt, uint4* bb) {
#pragma unroll
        for (int kf = 0; kf < 2; ++kf)
#pragma unroll
          for (int ct = 0; ct < 4; ++ct)
            bb[kf * 4 + ct] = Wg[(size_t)(kt * 8 + kf * 4 + kcl) * 128 +
                                 wc * 64 + ct * 16 + l15];
      };
      auto COMPUTE = [&](int bf, const uint4* bb) {
        uint4 af[2][2];
#pragma unroll
        for (int kf = 0; kf < 2; ++kf)
#pragma unroll
          for (int rt = 0; rt < 2; ++rt)
            af[kf][rt] = sA[bf][kf * 4 + kcl][wr * 32 + rt * 16 + l15];
#pragma unroll
        for (int kf = 0; kf < 2; ++kf)
#pragma unroll
          for (int rt = 0; rt < 2; ++rt)
#pragma unroll
            for (int ct = 0; ct < 4; ++ct)
              acc[rt][ct] = __builtin_amdgcn_mfma_f32_16x16x32_f16(
                  as_f16x8(af[kf][rt]), as_f16x8(bb[kf * 4 + ct]), acc[rt][ct],
                  0, 0, 0);
      };

      XLOAD(0, xva);
      XLOAD(1, xvb);
      BLOAD(0, br0);
      XWRITE(0, xva);
      __syncthreads();

#pragma unroll 1
      for (int kt = 0; kt < GNKT; kt += 2) {
        BLOAD(kt + 1, br1);
        if (kt + 2 < GNKT) XLOAD(kt + 2, xva);
        COMPUTE(0, br0);
        XWRITE(1, xvb);
        __syncthreads();
        if (kt + 2 < GNKT) BLOAD(kt + 2, br0);
        if (kt + 3 < GNKT) XLOAD(kt + 3, xvb);
        COMPUTE(1, br1);
        if (kt + 2 < GNKT) {
          XWRITE(0, xva);
          __syncthreads();
        }
      }

      // single-writer store of xw[t][b][h] + release flag
      const int rbase = wr * 32 + (lane >> 4) * 4;  // batch row
      half_t* xwt = xw + (size_t)t * (BATCH * HIDDEN);
#pragma unroll
      for (int rt = 0; rt < 2; ++rt)
#pragma unroll
        for (int ct = 0; ct < 4; ++ct) {
          const int col = wc * 64 + ct * 16 + l15;
#pragma unroll
          for (int j = 0; j < 4; ++j) {
            const int row = rbase + rt * 16 + j;
            xwt[(size_t)row * HIDDEN + col] =
                (half_t)(acc[rt][ct][j] + bias_c[ct]);
          }
        }
      __syncthreads();  // drain all waves' stores before release
      if (tid == 0)
        __hip_atomic_store(&flags[t], 1, __ATOMIC_RELEASE,
                           __HIP_MEMORY_SCOPE_AGENT);
      __syncthreads();
    }
    return;
  }

  // ========================= rec (R11-exact STEP) =========================
  const int blk = blockIdx.x;    // 0..3
  const int bl = lane & 15;      // batch-local
  const int kg = lane >> 4;      // k-group
  const int swz = (bl & 7) << 4; // LDS XOR swizzle

  uint4 afr[2][4];
#pragma unroll
  for (int mi = 0; mi < 2; ++mi)
#pragma unroll
    for (int kt = 0; kt < 4; ++kt)
      afr[mi][kt] = *(const uint4*)(Whh2 + ((size_t)((2 * w + mi) * 16 + bl)) * 64 +
                                    kt * 16 + kg * 4);

#pragma unroll
  for (int i = 0; i < 4; ++i) ((unsigned int*)st)[tid + 256 * i] = 0u;
  __syncthreads();

  // xw layout [t][b][h]: per-t stride = 8192 elements
  const half_t* xb0 = xw + (size_t)(blk * RB + bl) * HIDDEN + w * 32 + kg * 4;
  const half_t* xb1 = xb0 + 16;
#define TSTR ((size_t)(BATCH * HIDDEN))

  float hh[2][4];

  auto aload = [&](int tt) {
    return __hip_atomic_load(&flags[tt], __ATOMIC_ACQUIRE,
                             __HIP_MEMORY_SCOPE_AGENT);
  };

  auto STEP = [&](const half_t* stR, half_t* stW, ushort4 xc0, ushort4 xc1) {
    uint4 bfr[4];
#pragma unroll
    for (int kt = 0; kt < 4; ++kt) {
      const int off = (bl * 256 + kt * 64 + kg * 16) ^ swz;
      bfr[kt] = *(const uint4*)((const char*)stR + off);
    }
    f32x4 a0, a1;
    a0[0] = h2f(xc0.x); a0[1] = h2f(xc0.y); a0[2] = h2f(xc0.z); a0[3] = h2f(xc0.w);
    a1[0] = h2f(xc1.x); a1[1] = h2f(xc1.y); a1[2] = h2f(xc1.z); a1[3] = h2f(xc1.w);
#pragma unroll
    for (int kt = 0; kt < 4; ++kt) {
      a0 = __builtin_amdgcn_mfma_f32_16x16x32_f16(as_f16x8(afr[0][kt]),
                                                  as_f16x8(bfr[kt]), a0, 0, 0, 0);
      a1 = __builtin_amdgcn_mfma_f32_16x16x32_f16(as_f16x8(afr[1][kt]),
                                                  as_f16x8(bfr[kt]), a1, 0, 0, 0);
    }
#pragma unroll
    for (int j = 0; j < 4; ++j) {
      hh[0][j] = tanh_fast(a0[j]);
      hh[1][j] = tanh_fast(a1[j]);
    }
    uint2 p0 = {h2u(pkrtz(hh[0][0], hh[0][1])), h2u(pkrtz(hh[0][2], hh[0][3]))};
    uint2 p1 = {h2u(pkrtz(hh[1][0], hh[1][1])), h2u(pkrtz(hh[1][2], hh[1][3]))};
    const int w0 = (bl * 256 + (2 * w + 0) * 32 + kg * 8) ^ swz;
    const int w1 = (bl * 256 + (2 * w + 1) * 32 + kg * 8) ^ swz;
    *(uint2*)((char*)stW + w0) = p0;
    *(uint2*)((char*)stW + w1) = p1;
    __syncthreads();
  };

  // prologue: wait for t=0,1
  while (aload(0) != 1) __builtin_amdgcn_s_sleep(2);
  ushort4 xA0 = *(const ushort4*)(xb0);
  ushort4 xA1 = *(const ushort4*)(xb1);
  while (aload(1) != 1) __builtin_amdgcn_s_sleep(2);
  ushort4 xB0 = *(const ushort4*)(xb0 + TSTR);
  ushort4 xB1 = *(const ushort4*)(xb1 + TSTR);

  for (int t2 = 0; t2 < TSTEPS; t2 += 2) {
    const ushort4 c0 = xA0, c1 = xA1;
    int f2 = (t2 + 2 < TSTEPS) ? aload(t2 + 2) : 1;
    STEP(&st[0][0][0], &st[1][0][0], c0, c1);
    if (t2 + 2 < TSTEPS) {
      while (f2 != 1) { __builtin_amdgcn_s_sleep(1); f2 = aload(t2 + 2); }
      xA0 = *(const ushort4*)(xb0 + (size_t)(t2 + 2) * TSTR);
      xA1 = *(const ushort4*)(xb1 + (size_t)(t2 + 2) * TSTR);
    }
    const ushort4 d0 = xB0, d1 = xB1;
    int f3 = (t2 + 3 < TSTEPS) ? aload(t2 + 3) : 1;
    STEP(&st[1][0][0], &st[0][0][0], d0, d1);
    if (t2 + 3 < TSTEPS) {
      while (f3 != 1) { __builtin_amdgcn_s_sleep(1); f3 = aload(t2 + 3); }
      xB0 = *(const ushort4*)(xb0 + (size_t)(t2 + 3) * TSTR);
      xB1 = *(const ushort4*)(xb1 + (size_t)(t2 + 3) * TSTR);
    }
  }

  const float4 wf0 = *(const float4*)&W_fc[(2 * w + 0) * 16 + kg * 4];
  const float4 wf1 = *(const float4*)&W_fc[(2 * w + 1) * 16 + kg * 4];
  float partial = hh[0][0] * wf0.x + hh[0][1] * wf0.y + hh[0][2] * wf0.z +
                  hh[0][3] * wf0.w + hh[1][0] * wf1.x + hh[1][1] * wf1.y +
                  hh[1][2] * wf1.z + hh[1][3] * wf1.w;
  red[tid] = partial;
  __syncthreads();
  if (tid < RB) {
    float ssum = b_fc[0];
#pragma unroll
    for (int q = 0; q < 16; ++q) ssum += red[q * 16 + tid];
    out[blk * RB + tid] = ssum;
  }
}

extern "C" void kernel_launch(void* const* d_in, const int* in_sizes, int n_in,
                              void* d_out, int out_size, void* d_ws, size_t ws_size,
                              hipStream_t stream) {
  const float* x    = (const float*)d_in[0];
  const float* W_ih = (const float*)d_in[1];
  const float* W_hh = (const float*)d_in[2];
  const float* b_ih = (const float*)d_in[3];
  const float* b_hh = (const float*)d_in[4];
  const float* W_fc = (const float*)d_in[5];
  const float* b_fc = (const float*)d_in[6];

  char* ws = (char*)d_ws;
  int*          flags = (int*)ws;                                   // 4 KB
  half_t*       xwf16 = (half_t*)(ws + 4096);                       // 8 MB
  uint4*        Wg    = (uint4*)(ws + 4096 + (8u << 20));           // 512 KB
  unsigned int* Whh2  = (unsigned int*)(ws + 4096 + (8u << 20) + (512u << 10));

  hipMemsetAsync(ws, 0, 4096, stream);  // reset flags each launch
  prep_kernel<<<128, 256, 0, stream>>>(W_ih, W_hh, Wg, Whh2);
  fused_kernel<<<4 + NPROD, 256, 0, stream>>>(
      x, Wg, Whh2, b_ih, b_hh, W_fc, b_fc, xwf16, flags, (float*)d_out);
}

// Round 16
// 259.544 us; speedup vs baseline: 2.8808x; 2.3161x over previous
//
#include <hip/hip_runtime.h>
#include <hip/hip_bf16.h>
#include <math.h>

#define INPUT 2048
#define HIDDEN 128
#define BATCH 64
#define TSTEPS 512
#define RB 16

typedef _Float16 half_t;
typedef __attribute__((ext_vector_type(2))) _Float16 half2_t;
typedef __attribute__((ext_vector_type(8))) _Float16 f16x8;
typedef __attribute__((ext_vector_type(4))) float f32x4;

static __device__ __forceinline__ f16x8 as_f16x8(uint4 v) {
  return __builtin_bit_cast(f16x8, v);
}
static __device__ __forceinline__ unsigned int h2u(half2_t v) {
  return __builtin_bit_cast(unsigned int, v);
}
static __device__ __forceinline__ half2_t pkrtz(float a, float b) {
  return __builtin_bit_cast(half2_t, __builtin_amdgcn_cvt_pkrtz(a, b));
}
static __device__ __forceinline__ float h2f(unsigned short u) {
  return (float)__builtin_bit_cast(half_t, u);
}

// tanh(x) = 1 - 2/(e^{2x}+1); e^{2x} = 2^{x*2/ln2}. Saturates correctly.
static __device__ __forceinline__ float tanh_fast(float x) {
#if __has_builtin(__builtin_amdgcn_exp2f)
  const float e = __builtin_amdgcn_exp2f(x * 2.885390082f);
#else
  const float e = exp2f(x * 2.885390082f);
#endif
  return 1.f - 2.f * __builtin_amdgcn_rcpf(e + 1.f);
}

// Barrier that does NOT drain vmcnt: LDS visibility only (lgkmcnt), so the
// depth-2 global xw prefetch loads stay in flight across the barrier.
// (__syncthreads would emit s_waitcnt vmcnt(0) and stall on them each step.)
static __device__ __forceinline__ void barrier_lds_only() {
  asm volatile("s_waitcnt lgkmcnt(0)" ::: "memory");
  __builtin_amdgcn_s_barrier();
}

// ---------------------------------------------------------------------------
// Prep: W_ih f32 -> Wg granule layout; W_hh f32 -> packed half2 (k-major).
// ---------------------------------------------------------------------------
__global__ __launch_bounds__(256) void prep_kernel(
    const float* __restrict__ W_ih, const float* __restrict__ W_hh,
    uint4* __restrict__ Wg, unsigned int* __restrict__ Whh2) {
  const int id = blockIdx.x * 256 + threadIdx.x;  // 32768 threads
  const int col = id & 127;
  const int kc = id >> 7;  // 0..255
  const float4 a = *(const float4*)(W_ih + (size_t)col * INPUT + kc * 8);
  const float4 b = *(const float4*)(W_ih + (size_t)col * INPUT + kc * 8 + 4);
  uint4 q = {h2u(pkrtz(a.x, a.y)), h2u(pkrtz(a.z, a.w)),
             h2u(pkrtz(b.x, b.y)), h2u(pkrtz(b.z, b.w))};
  Wg[(size_t)kc * 128 + col] = q;
  if (id < 8192) {
    float2 p = ((const float2*)W_hh)[id];
    half_t ha = (half_t)p.x, hb = (half_t)p.y;
    Whh2[id] = (unsigned int)__builtin_bit_cast(unsigned short, ha) |
               ((unsigned int)__builtin_bit_cast(unsigned short, hb) << 16);
  }
}

// ---------------------------------------------------------------------------
// GEMM (R10/R11 form, measured ~70 us): A LDS-staged depth-2, B direct L2.
// ---------------------------------------------------------------------------
#define GBM 64
#define GBK 64
#define GNKT (INPUT / GBK)  // 32

__global__ __launch_bounds__(256) void gemm_xw_f16(
    const float* __restrict__ x, const uint4* __restrict__ Wg,
    const float* __restrict__ b_ih, const float* __restrict__ b_hh,
    half_t* __restrict__ xw) {
  __shared__ uint4 sA[2][8][64];  // [buf][kc][m]  16 KB

  const int tid = threadIdx.x;
  const int lane = tid & 63;
  const int w = tid >> 6;
  const int wr = w >> 1, wc = w & 1;
  const int block_row = blockIdx.x * GBM;
  const int kcl = lane >> 4;
  const int l15 = lane & 15;

  const int xm = tid & 63, xkq = tid >> 6;
  const float* xsrc = x + (size_t)(block_row + xm) * INPUT + xkq * 16;

  f32x4 acc[2][4];
#pragma unroll
  for (int rt = 0; rt < 2; ++rt)
#pragma unroll
    for (int ct = 0; ct < 4; ++ct) acc[rt][ct] = (f32x4)0.f;

  float bias_c[4];
#pragma unroll
  for (int ct = 0; ct < 4; ++ct) {
    const int col = wc * 64 + ct * 16 + l15;
    bias_c[ct] = b_ih[col] + b_hh[col];
  }

  float4 xva[4], xvb[4];
  uint4 br0[8], br1[8];

  auto XLOAD = [&](int kt, float4* xv) {
    const float4* xs = (const float4*)(xsrc + kt * GBK);
#pragma unroll
    for (int j = 0; j < 4; ++j) xv[j] = xs[j];
  };
  auto XWRITE = [&](int bf, const float4* xv) {
#pragma unroll
    for (int g = 0; g < 2; ++g) {
      uint4 q = {h2u(pkrtz(xv[2 * g].x, xv[2 * g].y)),
                 h2u(pkrtz(xv[2 * g].z, xv[2 * g].w)),
                 h2u(pkrtz(xv[2 * g + 1].x, xv[2 * g + 1].y)),
                 h2u(pkrtz(xv[2 * g + 1].z, xv[2 * g + 1].w))};
      sA[bf][xkq * 2 + g][xm] = q;
    }
  };
  auto BLOAD = [&](int kt, uint4* bb) {
#pragma unroll
    for (int kf = 0; kf < 2; ++kf)
#pragma unroll
      for (int ct = 0; ct < 4; ++ct)
        bb[kf * 4 + ct] =
            Wg[(size_t)(kt * 8 + kf * 4 + kcl) * 128 + wc * 64 + ct * 16 + l15];
  };
  auto COMPUTE = [&](int bf, const uint4* bb) {
    uint4 af[2][2];
#pragma unroll
    for (int kf = 0; kf < 2; ++kf)
#pragma unroll
      for (int rt = 0; rt < 2; ++rt)
        af[kf][rt] = sA[bf][kf * 4 + kcl][wr * 32 + rt * 16 + l15];
#pragma unroll
    for (int kf = 0; kf < 2; ++kf)
#pragma unroll
      for (int rt = 0; rt < 2; ++rt)
#pragma unroll
        for (int ct = 0; ct < 4; ++ct)
          acc[rt][ct] = __builtin_amdgcn_mfma_f32_16x16x32_f16(
              as_f16x8(af[kf][rt]), as_f16x8(bb[kf * 4 + ct]), acc[rt][ct], 0, 0, 0);
  };

  XLOAD(0, xva);
  XLOAD(1, xvb);
  BLOAD(0, br0);
  XWRITE(0, xva);
  __syncthreads();

#pragma unroll 1
  for (int kt = 0; kt < GNKT; kt += 2) {
    BLOAD(kt + 1, br1);
    if (kt + 2 < GNKT) XLOAD(kt + 2, xva);
    COMPUTE(0, br0);
    XWRITE(1, xvb);
    __syncthreads();
    if (kt + 2 < GNKT) BLOAD(kt + 2, br0);
    if (kt + 3 < GNKT) XLOAD(kt + 3, xvb);
    COMPUTE(1, br1);
    if (kt + 2 < GNKT) {
      XWRITE(0, xva);
      __syncthreads();
    }
  }

  const int rbase = block_row + wr * 32 + (lane >> 4) * 4;
#pragma unroll
  for (int rt = 0; rt < 2; ++rt)
#pragma unroll
    for (int ct = 0; ct < 4; ++ct) {
      const int col = wc * 64 + ct * 16 + l15;
#pragma unroll
      for (int j = 0; j < 4; ++j) {
        const int row = rbase + rt * 16 + j;
        xw[(size_t)row * HIDDEN + col] = (half_t)(acc[rt][ct][j] + bias_c[ct]);
      }
    }
}

// ---------------------------------------------------------------------------
// Recurrence via MFMA — R11 structure (186 us) with ONE change: the per-step
// barrier no longer drains vmcnt (barrier_lds_only), so the depth-2 global
// xw prefetch stays in flight across barriers instead of stalling each step.
// ---------------------------------------------------------------------------
__global__ __launch_bounds__(256) void rnn_rec_mfma(
    const half_t* __restrict__ xw, const unsigned int* __restrict__ Whh2,
    const float* __restrict__ W_fc, const float* __restrict__ b_fc,
    float* __restrict__ out) {
  const int blk = blockIdx.x;    // 0..3
  const int tid = threadIdx.x;
  const int lane = tid & 63;
  const int w = tid >> 6;        // wave 0..3 -> h' tiles 2w, 2w+1
  const int bl = lane & 15;      // batch-local 0..15
  const int g = lane >> 4;       // k-group 0..3
  const int swz = (bl & 7) << 4; // LDS XOR swizzle (bits 4..6)

  __shared__ half_t st[2][RB][HIDDEN];  // 8 KB state double buffer
  __shared__ float red[256];

  uint4 afr[2][4];
#pragma unroll
  for (int mi = 0; mi < 2; ++mi)
#pragma unroll
    for (int kt = 0; kt < 4; ++kt)
      afr[mi][kt] = *(const uint4*)(Whh2 + ((size_t)((2 * w + mi) * 16 + bl)) * 64 +
                                    kt * 16 + g * 4);

#pragma unroll
  for (int i = 0; i < 4; ++i) ((unsigned int*)st)[tid + 256 * i] = 0u;
  __syncthreads();

  const half_t* xb0 = xw + ((size_t)(blk * RB + bl) * TSTEPS) * HIDDEN + w * 32 + g * 4;
  const half_t* xb1 = xb0 + 16;

  float hh[2][4];

  auto STEP = [&](const half_t* stR, half_t* stW, ushort4 xc0, ushort4 xc1) {
    uint4 bfr[4];
#pragma unroll
    for (int kt = 0; kt < 4; ++kt) {
      const int off = (bl * 256 + kt * 64 + g * 16) ^ swz;
      bfr[kt] = *(const uint4*)((const char*)stR + off);
    }
    f32x4 a0, a1;
    a0[0] = h2f(xc0.x); a0[1] = h2f(xc0.y); a0[2] = h2f(xc0.z); a0[3] = h2f(xc0.w);
    a1[0] = h2f(xc1.x); a1[1] = h2f(xc1.y); a1[2] = h2f(xc1.z); a1[3] = h2f(xc1.w);
#pragma unroll
    for (int kt = 0; kt < 4; ++kt) {
      a0 = __builtin_amdgcn_mfma_f32_16x16x32_f16(as_f16x8(afr[0][kt]),
                                                  as_f16x8(bfr[kt]), a0, 0, 0, 0);
      a1 = __builtin_amdgcn_mfma_f32_16x16x32_f16(as_f16x8(afr[1][kt]),
                                                  as_f16x8(bfr[kt]), a1, 0, 0, 0);
    }
#pragma unroll
    for (int j = 0; j < 4; ++j) {
      hh[0][j] = tanh_fast(a0[j]);
      hh[1][j] = tanh_fast(a1[j]);
    }
    uint2 p0 = {h2u(pkrtz(hh[0][0], hh[0][1])), h2u(pkrtz(hh[0][2], hh[0][3]))};
    uint2 p1 = {h2u(pkrtz(hh[1][0], hh[1][1])), h2u(pkrtz(hh[1][2], hh[1][3]))};
    const int w0 = (bl * 256 + (2 * w + 0) * 32 + g * 8) ^ swz;
    const int w1 = (bl * 256 + (2 * w + 1) * 32 + g * 8) ^ swz;
    *(uint2*)((char*)stW + w0) = p0;
    *(uint2*)((char*)stW + w1) = p1;
    barrier_lds_only();  // LDS-visibility barrier; vmcnt NOT drained
  };

  ushort4 xA0 = *(const ushort4*)(xb0);
  ushort4 xA1 = *(const ushort4*)(xb1);
  ushort4 xB0 = *(const ushort4*)(xb0 + HIDDEN);
  ushort4 xB1 = *(const ushort4*)(xb1 + HIDDEN);

  for (int t2 = 0; t2 < TSTEPS; t2 += 2) {
    ushort4 c0 = xA0, c1 = xA1;
    xA0 = *(const ushort4*)(xb0 + (size_t)(t2 + 2) * HIDDEN);
    xA1 = *(const ushort4*)(xb1 + (size_t)(t2 + 2) * HIDDEN);
    STEP(&st[0][0][0], &st[1][0][0], c0, c1);

    ushort4 d0 = xB0, d1 = xB1;
    xB0 = *(const ushort4*)(xb0 + (size_t)(t2 + 3) * HIDDEN);
    xB1 = *(const ushort4*)(xb1 + (size_t)(t2 + 3) * HIDDEN);
    STEP(&st[1][0][0], &st[0][0][0], d0, d1);
  }

  const float4 wf0 = *(const float4*)&W_fc[(2 * w + 0) * 16 + g * 4];
  const float4 wf1 = *(const float4*)&W_fc[(2 * w + 1) * 16 + g * 4];
  float partial = hh[0][0] * wf0.x + hh[0][1] * wf0.y + hh[0][2] * wf0.z +
                  hh[0][3] * wf0.w + hh[1][0] * wf1.x + hh[1][1] * wf1.y +
                  hh[1][2] * wf1.z + hh[1][3] * wf1.w;
  red[tid] = partial;
  __syncthreads();
  if (tid < RB) {
    float s = b_fc[0];
#pragma unroll
    for (int q = 0; q < 16; ++q) s += red[q * 16 + tid];
    out[blk * RB + tid] = s;
  }
}

extern "C" void kernel_launch(void* const* d_in, const int* in_sizes, int n_in,
                              void* d_out, int out_size, void* d_ws, size_t ws_size,
                              hipStream_t stream) {
  const float* x    = (const float*)d_in[0];
  const float* W_ih = (const float*)d_in[1];
  const float* W_hh = (const float*)d_in[2];
  const float* b_ih = (const float*)d_in[3];
  const float* b_hh = (const float*)d_in[4];
  const float* W_fc = (const float*)d_in[5];
  const float* b_fc = (const float*)d_in[6];

  char* ws = (char*)d_ws;
  half_t*       xwf16 = (half_t*)ws;                                     // 8 MB
  uint4*        Wg    = (uint4*)(ws + (8u << 20));                       // 512 KB
  unsigned int* Whh2  = (unsigned int*)(ws + (8u << 20) + (512u << 10)); // 32 KB

  prep_kernel<<<128, 256, 0, stream>>>(W_ih, W_hh, Wg, Whh2);
  gemm_xw_f16<<<(BATCH * TSTEPS) / GBM, 256, 0, stream>>>(x, Wg, b_ih, b_hh, xwf16);
  rnn_rec_mfma<<<BATCH / RB, 256, 0, stream>>>(xwf16, Whh2, W_fc, b_fc, (float*)d_out);
}